// Round 1
// baseline (159.568 us; speedup 1.0000x reference)
//
#include <hip/hip_runtime.h>
#include <hip/hip_bf16.h>

typedef __attribute__((ext_vector_type(8))) short short8;
typedef __attribute__((ext_vector_type(4))) float f32x4;
typedef unsigned short u16;
typedef unsigned int u32;

// ---- constants ----
// B=512, M=40, H=128, D=64, C=128, K' = M*H = 5120, 160 K-tiles of 32.
#define NB 512
#define NM 40
#define NH 128
#define ND 64
#define NC 128
#define KTOT 5120
#define NT 160
// xkT padded row: 136 shorts (272 B = 68 words -> conflict-free b128 reads)
#define XKP 136

__device__ __forceinline__ u16 f2bf_rne(float f) {
    u32 u = __float_as_uint(f);
    u32 r = u + 0x7FFFu + ((u >> 16) & 1u);
    return (u16)(r >> 16);
}
__device__ __forceinline__ float bf2f(short s) {
    return __uint_as_float(((u32)(u16)s) << 16);
}

// b_frag[j] = bf16_trunc(s * bf16(xv[j]))  -- 1 v_perm packs 2 elements
__device__ __forceinline__ short8 bmul(float s, short8 xv) {
    union { short8 s8; u32 u4[4]; } r;
#pragma unroll
    for (int j = 0; j < 4; ++j) {
        float f0 = s * bf2f(xv[2 * j]);
        float f1 = s * bf2f(xv[2 * j + 1]);
        r.u4[j] = __builtin_amdgcn_perm(__float_as_uint(f1), __float_as_uint(f0),
                                        0x07060302u);
    }
    return r.s8;
}

// ---- pre-kernel 1: gather W (fp32 [C][H*40+m]) into bf16 W3 in per-tile
// linear order: W3[t][q][c][j] = bf16(W[c][h*40+m]), k' = t*32+q*8+j = m*128+h
__global__ void w3_kernel(const float* __restrict__ W, u16* __restrict__ W3) {
    int n = blockIdx.x * 256 + threadIdx.x;          // < 655360
    int t = n >> 12;
    int rem = n & 4095;
    int q = rem >> 10;
    int c = (rem >> 3) & 127;
    int j = n & 7;
    int kp = t * 32 + q * 8 + j;                     // k' = m*128 + h
    int m = kp >> 7;
    int h = kp & 127;
    W3[n] = f2bf_rne(W[c * KTOT + h * NM + m]);
}

// ---- pre-kernel 2: transpose xk fp32 [b][128][64] -> bf16 xkT [b][64][136]
__global__ void xkt_kernel(const float* __restrict__ xk, u16* __restrict__ xkT) {
    __shared__ float lds[128 * 65];
    int b = blockIdx.x;
    const float* src = xk + (size_t)b * (NH * ND);
    for (int i = threadIdx.x; i < NH * ND; i += 256)
        lds[(i >> 6) * 65 + (i & 63)] = src[i];
    __syncthreads();
    u16* dst = xkT + (size_t)b * (ND * XKP);
    for (int o = threadIdx.x; o < ND * XKP; o += 256) {
        int d = o / XKP;
        int h = o - d * XKP;
        float v = (h < NH) ? lds[h * 65 + d] : 0.f;
        dst[o] = f2bf_rne(v);
    }
}

// ---- main kernel: 1 block per batch, 256 threads (4 waves), 16x16x32 MFMA
__global__ void __launch_bounds__(256, 2) cin_main(
    const float* __restrict__ x0g, const float* __restrict__ biasg,
    const u16* __restrict__ W3, const u16* __restrict__ xkTg,
    float* __restrict__ out)
{
    __shared__ __align__(16) short A2[2][4096];   // [buf][q][c][8] bf16, 2x8KB
    __shared__ __align__(16) short xkT[ND * XKP]; // [d][136] bf16, 17408 B
    __shared__ __align__(16) float x0s[NM * ND];  // [m][d] f32, 10240 B
    __shared__ float bias_s[NC];

    const int tid = threadIdx.x;
    const int b = blockIdx.x;
    const int w = tid >> 6, L = tid & 63;
    const int q = L >> 4, l16 = L & 15;
    const int rowbase = (w >> 1) << 6;   // wave tile: 64 rows x 32 cols
    const int colbase = (w & 1) << 5;
    const int dcol0 = colbase + l16, dcol1 = dcol0 + 16;

    // one-time staging (plain loads; covered by first loop barrier)
    {
        const float* xp = x0g + (size_t)b * (NM * ND);
        for (int i = tid; i < NM * ND; i += 256) x0s[i] = xp[i];
        const u32* src = (const u32*)(xkTg + (size_t)b * (ND * XKP));
        u32* dst = (u32*)xkT;
        for (int i = tid; i < (ND * XKP) / 2; i += 256) dst[i] = src[i];
        if (tid < NC) bias_s[tid] = biasg[tid];
    }

    // async A-tile stage: 8 KB per tile, 512 x 16B chunks, lane-linear
    auto stageA = [&](int t, int bb) {
#pragma unroll
        for (int r = 0; r < 2; ++r) {
            int n = r * 256 + w * 64;                 // wave-uniform chunk base
            const u16* g = W3 + (size_t)t * 4096 + (size_t)(n + L) * 8;
            __builtin_amdgcn_global_load_lds(
                (const __attribute__((address_space(1))) void*)g,
                (__attribute__((address_space(3))) void*)(&A2[bb][n * 8]),
                16, 0, 0);
        }
    };

    f32x4 acc[4][2] = {};
    float x0v0 = 0.f, x0v1 = 0.f;

    stageA(0, 0);

#pragma unroll 4
    for (int t = 0; t < NT; ++t) {
        __syncthreads();                       // drains stage(t) + frees old buf
        if (t + 1 < NT) stageA(t + 1, (t + 1) & 1);
        const int bb = t & 1;
        if ((t & 3) == 0) {                    // m advances every 4 K-tiles
            const int m = t >> 2;
            x0v0 = x0s[m * ND + dcol0];
            x0v1 = x0s[m * ND + dcol1];
        }
        const int hh = ((t & 3) << 5) + q * 8; // h0 + quad*8
        short8 xv0 = *(const short8*)&xkT[dcol0 * XKP + hh];
        short8 xv1 = *(const short8*)&xkT[dcol1 * XKP + hh];
        short8 bf0 = bmul(x0v0, xv0);
        short8 bf1 = bmul(x0v1, xv1);
        const short* Ab = &A2[bb][q * 1024 + (rowbase + l16) * 8];
#pragma unroll
        for (int mt = 0; mt < 4; ++mt) {
            short8 a = *(const short8*)(Ab + mt * 128);
            acc[mt][0] = __builtin_amdgcn_mfma_f32_16x16x32_bf16(a, bf0, acc[mt][0], 0, 0, 0);
            acc[mt][1] = __builtin_amdgcn_mfma_f32_16x16x32_bf16(a, bf1, acc[mt][1], 0, 0, 0);
        }
    }

    // epilogue: C/D layout col = lane&15, row = quad*4 + reg
    float* op = out + (size_t)b * (NC * ND);
#pragma unroll
    for (int mt = 0; mt < 4; ++mt) {
        int c = rowbase + mt * 16 + q * 4;
#pragma unroll
        for (int r = 0; r < 4; ++r) {
            float bv = bias_s[c + r];
            op[(c + r) * ND + dcol0] = acc[mt][0][r] + bv;
            op[(c + r) * ND + dcol1] = acc[mt][1][r] + bv;
        }
    }
}

extern "C" void kernel_launch(void* const* d_in, const int* in_sizes, int n_in,
                              void* d_out, int out_size, void* d_ws, size_t ws_size,
                              hipStream_t stream) {
    const float* x0 = (const float*)d_in[0];
    const float* xk = (const float*)d_in[1];
    const float* W  = (const float*)d_in[2];
    const float* bi = (const float*)d_in[3];
    float* out = (float*)d_out;

    u16* W3  = (u16*)d_ws;                       // 655360 shorts = 1.31 MB
    u16* xkT = (u16*)d_ws + 655360;              // 512*8704 shorts = 8.9 MB

    w3_kernel<<<2560, 256, 0, stream>>>(W, W3);
    xkt_kernel<<<NB, 256, 0, stream>>>(xk, xkT);
    cin_main<<<NB, 256, 0, stream>>>(x0, bi, W3, xkT, out);
}